// Round 13
// baseline (189.188 us; speedup 1.0000x reference)
//
#include <hip/hip_runtime.h>
#include <math.h>

#define BB 32
#define LL 512
#define HH 768
#define PP 5
#define KK 5
#define CC 4
#define NN (BB*PP)   // 160

__device__ __forceinline__ float wredf(float v) {
  #pragma unroll
  for (int off = 32; off; off >>= 1) v += __shfl_xor(v, off, 64);
  return v;
}
__device__ __forceinline__ double wredd(double v) {
  #pragma unroll
  for (int off = 32; off; off >>= 1) v += __shfl_xor(v, off, 64);
  return v;
}

// ==== node 1: cs_raw (4096 blocks) + pnorm (5) + diversity (10) + zero counter/numzz
__global__ __launch_bounds__(256) void k1f(const float* __restrict__ emb,
    const float* __restrict__ proto, float* __restrict__ cs,
    float* __restrict__ pnorm, float* __restrict__ divp,
    int* __restrict__ counter, float* __restrict__ numzz)
{
  __shared__ float s_red[4];
  int tid = threadIdx.x, lane = tid & 63, wid = tid >> 6, bid = blockIdx.x;
  if (bid < 4096) {
    // wave per token: cs_raw[b*5+p][l] = dot(emb[b,l], proto[p]) / |emb[b,l]|
    int gw = bid * 4 + wid, b = gw >> 9, l = gw & 511;
    const float4* e4  = (const float4*)(emb + ((size_t)b * LL + l) * HH);
    const float4* pr4 = (const float4*)proto;
    float ss = 0, acc[PP] = {0, 0, 0, 0, 0};
    #pragma unroll
    for (int i = 0; i < 3; i++) {
      int idx = lane + i * 64;
      float4 x = e4[idx];
      ss = fmaf(x.x, x.x, fmaf(x.y, x.y, fmaf(x.z, x.z, fmaf(x.w, x.w, ss))));
      #pragma unroll
      for (int p = 0; p < PP; p++) {
        float4 w = pr4[p * (HH/4) + idx];
        acc[p] = fmaf(x.x, w.x, fmaf(x.y, w.y, fmaf(x.z, w.z, fmaf(x.w, w.w, acc[p]))));
      }
    }
    #pragma unroll
    for (int off = 32; off; off >>= 1) {
      ss += __shfl_xor(ss, off, 64);
      #pragma unroll
      for (int p = 0; p < PP; p++) acc[p] += __shfl_xor(acc[p], off, 64);
    }
    if (lane == 0) {
      float inv = 1.0f / fmaxf(sqrtf(ss), 1e-12f);
      size_t base = ((size_t)b * PP) * LL + l;
      #pragma unroll
      for (int p = 0; p < PP; p++) cs[base + (size_t)p * LL] = acc[p] * inv;
    }
  } else {
    int aux = bid - 4096;
    if (aux == 15) {       // zero the k3 accumulators
      if (tid == 0) counter[0] = 0;
      if (tid < 2 * NN) numzz[tid] = 0.0f;
      return;
    }
    if (aux < PP) {                       // pnorm[aux]
      float ss = 0;
      for (int i = tid; i < HH; i += 256) { float v = proto[aux*HH + i]; ss = fmaf(v, v, ss); }
      ss = wredf(ss);
      if (lane == 0) s_red[wid] = ss;
      __syncthreads();
      if (tid == 0) pnorm[aux] = sqrtf(s_red[0] + s_red[1] + s_red[2] + s_red[3]);
    } else {                              // diversity pair
      const int pi_[10] = {0,0,0,0,1,1,1,2,2,3};
      const int pj_[10] = {1,2,3,4,2,3,4,3,4,4};
      int q = aux - PP, i = pi_[q], j = pj_[q];
      float ss = 0;
      for (int t = tid; t < HH; t += 256) {
        float d = proto[i*HH + t] - proto[j*HH + t];
        ss = fmaf(d, d, ss);
      }
      ss = wredf(ss);
      if (lane == 0) s_red[wid] = ss;
      __syncthreads();
      if (tid == 0) {
        float D = sqrtf(fmaxf(s_red[0] + s_red[1] + s_red[2] + s_red[3], 1e-12f));
        divp[q] = fmaxf(0.5f - D, 0.0f);
      }
    }
  }
}

// ==== node 2: per-row fused GEMV + MDN (160 blocks x 512 threads) — unchanged (R7/R10-verified)
__global__ __launch_bounds__(512) void k2f(
    const float* __restrict__ cs_g, const float* __restrict__ pnorm,
    const float* __restrict__ W1, const float* __restrict__ b1,
    const float* __restrict__ Wpi, const float* __restrict__ bpi,
    const float* __restrict__ Wmu, const float* __restrict__ bmu,
    const float* __restrict__ Wsig, const float* __restrict__ bsig,
    float* __restrict__ mask_g, float* __restrict__ denom_g, double* __restrict__ loss_rows)
{
  __shared__ float s_cs[LL], s_h[LL];
  __shared__ float s_out[16];
  __shared__ float s_par[32]; // logpi[0..4] pi[5..9] mu[10..14] logsig[15..19] invsig[20..24] sig[25..29]
  __shared__ float s_dn[8];
  int tid = threadIdx.x, lane = tid & 63, wid = tid >> 6, n = blockIdx.x;
  float invp = 1.0f / fmaxf(pnorm[n % PP], 1e-12f);
  s_cs[tid] = cs_g[(size_t)n * LL + tid] * invp;   // finish cosine: apply 1/|proto|
  __syncthreads();
  // GEMV: thread = column
  {
    float a0 = 0, a1 = 0, a2 = 0, a3 = 0;
    #pragma unroll 4
    for (int l = 0; l < LL; l += 4) {
      a0 = fmaf(s_cs[l+0], W1[(size_t)(l+0) * LL + tid], a0);
      a1 = fmaf(s_cs[l+1], W1[(size_t)(l+1) * LL + tid], a1);
      a2 = fmaf(s_cs[l+2], W1[(size_t)(l+2) * LL + tid], a2);
      a3 = fmaf(s_cs[l+3], W1[(size_t)(l+3) * LL + tid], a3);
    }
    s_h[tid] = tanhf((a0 + a1) + (a2 + a3) + b1[tid]);
  }
  __syncthreads();
  // 15 projection dots (8 waves, 2 rounds), double accumulation
  for (int o = wid; o < 15; o += 8) {
    int pj = o / 5, k = o % 5;
    const float* W  = (pj == 0) ? Wpi : ((pj == 1) ? Wmu : Wsig);
    const float* bb = (pj == 0) ? bpi : ((pj == 1) ? bmu : bsig);
    double acc = 0;
    for (int l = lane; l < LL; l += 64) acc += (double)s_h[l] * (double)W[l * KK + k];
    acc = wredd(acc);
    if (lane == 0) s_out[o] = (float)(acc + (double)bb[k]);
  }
  __syncthreads();
  if (tid == 0) {
    float x[KK], sh[KK], mx = -INFINITY;
    #pragma unroll
    for (int k = 0; k < KK; k++) { x[k] = s_out[k]; mx = fmaxf(mx, x[k]); }
    float se = 0;
    #pragma unroll
    for (int k = 0; k < KK; k++) { sh[k] = x[k] - mx; se += expf(sh[k]); }
    float lse = logf(se);
    #pragma unroll
    for (int k = 0; k < KK; k++) {
      float lp = sh[k] - lse;
      s_par[k]      = lp;
      s_par[5 + k]  = expf(lp);
      s_par[10 + k] = s_out[5 + k];
      float ls = s_out[10 + k];
      s_par[15 + k] = ls;
      float sg = expf(ls);
      s_par[25 + k] = sg;
      s_par[20 + k] = 1.0f / sg;
    }
  }
  __syncthreads();
  // wave 0: top-5 (JAX tie-break) + NLL in double
  if (wid == 0) {
    float v[8];
    #pragma unroll
    for (int i = 0; i < 8; i++) v[i] = s_cs[lane + i * 64];
    float ys[KK];
    for (int it = 0; it < KK; ++it) {
      float bv = v[0]; int bi = lane;
      #pragma unroll
      for (int i = 1; i < 8; i++) { if (v[i] > bv) { bv = v[i]; bi = lane + i * 64; } }
      #pragma unroll
      for (int off = 32; off; off >>= 1) {
        float ov = __shfl_xor(bv, off, 64);
        int   oi = __shfl_xor(bi, off, 64);
        if (ov > bv || (ov == bv && oi < bi)) { bv = ov; bi = oi; }
      }
      ys[it] = (float)bi;
      if ((bi & 63) == lane) v[bi >> 6] = -INFINITY;
    }
    double ll = 0;
    if (lane < KK) {
      double y = (double)ys[lane];
      double a[KK], m = -1e300;
      #pragma unroll
      for (int j = 0; j < KK; j++) {
        double z = (y - (double)s_par[10 + j]) / (double)s_par[25 + j];
        a[j] = (double)s_par[j] - 0.5 * z * z - (double)s_par[15 + j]
               - 0.91893853320467274178;  // 0.5*log(2*pi)
        if (a[j] > m) m = a[j];
      }
      double se = 0;
      #pragma unroll
      for (int j = 0; j < KK; j++) se += exp(a[j] - m);
      ll = m + log(se);
    }
    ll = wredd(ll);
    if (lane == 0) loss_rows[n] = ll;
  }
  // mask: one token position per thread
  {
    float t = (float)tid, d = 0;
    #pragma unroll
    for (int k = 0; k < KK; k++) {
      float zt = (t - s_par[10 + k]) * s_par[20 + k];
      d += s_par[5 + k] * expf(-0.5f * zt * zt) * s_par[20 + k];
    }
    d *= 0.39894228040143268f;   // 1/sqrt(2*pi)
    mask_g[(size_t)n * LL + tid] = d;
    float r = wredf(d);
    if (lane == 0) s_dn[wid] = r;
  }
  __syncthreads();
  if (tid == 0)
    denom_g[n] = fmaxf(s_dn[0]+s_dn[1]+s_dn[2]+s_dn[3]+s_dn[4]+s_dn[5]+s_dn[6]+s_dn[7], 1e-9f);
}

// ==== node 3: pooling (32 x 8 blocks, 96-h chunks = 100% CU coverage) + fused head
__global__ __launch_bounds__(512) void k3h(const float* __restrict__ hidden,
    const float* __restrict__ mask_g, const float* __restrict__ denom_g,
    const float* __restrict__ proto, const float* __restrict__ pnorm,
    const float* __restrict__ fcW, const float* __restrict__ fcb,
    const double* __restrict__ loss_rows, const float* __restrict__ divp,
    float* __restrict__ numzz, int* __restrict__ counter, float* __restrict__ out)
{
  __shared__ float s_m[PP][LL];        // 10 KB
  __shared__ float s_acc[8][PP][96];   // 15 KB
  __shared__ float s_sim[NN];
  __shared__ int s_last;
  int b = blockIdx.x, hc = blockIdx.y;          // hc in [0,8): 96-h chunks
  int tid = threadIdx.x, wid = tid >> 6, lane = tid & 63;
  for (int i = tid; i < PP * LL; i += 512) s_m[i >> 9][i & (LL - 1)] = mask_g[(size_t)b * PP * LL + i];
  __syncthreads();
  if (lane < 48) {
    int h0 = hc * 96 + lane * 2;
    const float* hp = hidden + (size_t)b * LL * HH + h0;
    float a0[PP] = {0,0,0,0,0}, a1[PP] = {0,0,0,0,0};
    int lbase = wid * 64;
    for (int i = 0; i < 64; i += 4) {
      int l = lbase + i;
      float4 m4[PP];
      #pragma unroll
      for (int p = 0; p < PP; p++) m4[p] = *(const float4*)&s_m[p][l];   // 16B aligned (l%4==0)
      #pragma unroll
      for (int ii = 0; ii < 4; ii++) {
        float2 hv = *(const float2*)(hp + (size_t)(l + ii) * HH);
        #pragma unroll
        for (int p = 0; p < PP; p++) {
          float m = ((const float*)&m4[p])[ii];   // static after unroll
          a0[p] = fmaf(hv.x, m, a0[p]); a1[p] = fmaf(hv.y, m, a1[p]);
        }
      }
    }
    #pragma unroll
    for (int p = 0; p < PP; p++) { s_acc[wid][p][lane*2] = a0[p]; s_acc[wid][p][lane*2+1] = a1[p]; }
  }
  __syncthreads();
  // epilogue: Z for (b, p, hc*96+hl) -> partial num/zz, 32-lane-group reduce, global atomics.
  if (tid < PP * 96) {                          // 480 items; p uniform per 32-lane group (96=3*32)
    int p = tid / 96, hl = tid % 96;
    float s = 0;
    #pragma unroll
    for (int w = 0; w < 8; w++) s += s_acc[w][p][hl];
    float z = s * (1.0f / 512.0f) / denom_g[b * PP + p];
    float np = z * proto[p * HH + hc * 96 + hl];
    float zp = z * z;
    #pragma unroll
    for (int off = 16; off; off >>= 1) { np += __shfl_xor(np, off, 64); zp += __shfl_xor(zp, off, 64); }
    if ((lane & 31) == 0) {
      atomicAdd(&numzz[(b * PP + p) * 2 + 0], np);
      atomicAdd(&numzz[(b * PP + p) * 2 + 1], zp);
    }
  }
  // __syncthreads drains vmcnt -> this block's atomics device-visible before counter bump
  __syncthreads();
  if (tid == 0) { __threadfence(); s_last = (atomicAdd(counter, 1) == (BB * 8 - 1)); }
  __syncthreads();
  if (s_last) {
    __threadfence();   // acquire: other blocks' numzz/loss writes
    for (int g = tid; g < NN; g += 512) {
      float num = numzz[2 * g], zz = numzz[2 * g + 1];
      s_sim[g] = num / fmaxf(sqrtf(zz) * pnorm[g % PP], 1e-6f);
    }
    __syncthreads();
    if (tid < BB * CC) {
      int bb2 = tid >> 2, c = tid & 3;
      float s = fcb[c];
      #pragma unroll
      for (int q = 0; q < PP; q++) s = fmaf(s_sim[bb2 * PP + q], fcW[q * CC + c], s);
      out[tid] = s;
    }
    if (wid == 2) {
      double s = 0;
      for (int i = lane; i < NN; i += 64) s += loss_rows[i];
      s = wredd(s);
      if (lane == 0) out[128] = (float)(-s / 800.0);
    }
    if (wid == 3) {
      float s = (lane < 10) ? divp[lane] : 0.0f;
      s = wredf(s);
      if (lane == 0) out[129] = s;
    }
  }
}

extern "C" void kernel_launch(void* const* d_in, const int* in_sizes, int n_in,
                              void* d_out, int out_size, void* d_ws, size_t ws_size,
                              hipStream_t stream)
{
  const float* emb   = (const float*)d_in[0];
  const float* hid   = (const float*)d_in[1];
  const float* proto = (const float*)d_in[2];
  const float* W1    = (const float*)d_in[3];
  const float* b1    = (const float*)d_in[4];
  const float* Wpi   = (const float*)d_in[5];
  const float* bpi   = (const float*)d_in[6];
  const float* Wmu   = (const float*)d_in[7];
  const float* bmu   = (const float*)d_in[8];
  const float* Wsig  = (const float*)d_in[9];
  const float* bsig  = (const float*)d_in[10];
  const float* fcW   = (const float*)d_in[11];
  const float* fcb   = (const float*)d_in[12];
  float* out = (float*)d_out;

  // ws layout (float offsets)
  double* loss_rows = (double*)d_ws;        // floats [0,320)
  float* wsf    = (float*)d_ws;
  float* divp   = wsf + 320;                // 10
  float* pnorm  = wsf + 330;                // 5
  int*   counter= (int*)(wsf + 336);        // 1
  float* numzz  = wsf + 352;                // 320 (num,zz per row)
  float* cs     = wsf + 1024;               // 81920
  float* maskb  = cs + (size_t)NN * LL;     // 81920
  float* denom  = maskb + (size_t)NN * LL;  // 160

  k1f<<<4112, 256, 0, stream>>>(emb, proto, cs, pnorm, divp, counter, numzz);
  k2f<<<NN, 512, 0, stream>>>(cs, pnorm, W1, b1, Wpi, bpi, Wmu, bmu, Wsig, bsig,
                              maskb, denom, loss_rows);
  k3h<<<dim3(BB, 8), 512, 0, stream>>>(hid, maskb, denom, proto, pnorm, fcW, fcb,
                                       loss_rows, divp, numzz, counter, out);
}

// Round 14
// 184.092 us; speedup vs baseline: 1.0277x; 1.0277x over previous
//
#include <hip/hip_runtime.h>
#include <math.h>

#define BB 32
#define LL 512
#define HH 768
#define PP 5
#define KK 5
#define CC 4
#define NN (BB*PP)   // 160

__device__ __forceinline__ float wredf(float v) {
  #pragma unroll
  for (int off = 32; off; off >>= 1) v += __shfl_xor(v, off, 64);
  return v;
}
__device__ __forceinline__ double wredd(double v) {
  #pragma unroll
  for (int off = 32; off; off >>= 1) v += __shfl_xor(v, off, 64);
  return v;
}

// ==== node 1: cs_raw (4096 blocks) + pnorm (5) + diversity (10) + zero counter/numzz
__global__ __launch_bounds__(256) void k1f(const float* __restrict__ emb,
    const float* __restrict__ proto, float* __restrict__ cs,
    float* __restrict__ pnorm, float* __restrict__ divp,
    int* __restrict__ counter, float* __restrict__ numzz)
{
  __shared__ float s_red[4];
  int tid = threadIdx.x, lane = tid & 63, wid = tid >> 6, bid = blockIdx.x;
  if (bid < 4096) {
    // wave per token: cs_raw[b*5+p][l] = dot(emb[b,l], proto[p]) / |emb[b,l]|
    int gw = bid * 4 + wid, b = gw >> 9, l = gw & 511;
    const float4* e4  = (const float4*)(emb + ((size_t)b * LL + l) * HH);
    const float4* pr4 = (const float4*)proto;
    float ss = 0, acc[PP] = {0, 0, 0, 0, 0};
    #pragma unroll
    for (int i = 0; i < 3; i++) {
      int idx = lane + i * 64;
      float4 x = e4[idx];
      ss = fmaf(x.x, x.x, fmaf(x.y, x.y, fmaf(x.z, x.z, fmaf(x.w, x.w, ss))));
      #pragma unroll
      for (int p = 0; p < PP; p++) {
        float4 w = pr4[p * (HH/4) + idx];
        acc[p] = fmaf(x.x, w.x, fmaf(x.y, w.y, fmaf(x.z, w.z, fmaf(x.w, w.w, acc[p]))));
      }
    }
    #pragma unroll
    for (int off = 32; off; off >>= 1) {
      ss += __shfl_xor(ss, off, 64);
      #pragma unroll
      for (int p = 0; p < PP; p++) acc[p] += __shfl_xor(acc[p], off, 64);
    }
    if (lane == 0) {
      float inv = 1.0f / fmaxf(sqrtf(ss), 1e-12f);
      size_t base = ((size_t)b * PP) * LL + l;
      #pragma unroll
      for (int p = 0; p < PP; p++) cs[base + (size_t)p * LL] = acc[p] * inv;
    }
  } else {
    int aux = bid - 4096;
    if (aux == 15) {       // zero the k3 accumulators
      if (tid == 0) counter[0] = 0;
      if (tid < 2 * NN) numzz[tid] = 0.0f;
      return;
    }
    if (aux < PP) {                       // pnorm[aux]
      float ss = 0;
      for (int i = tid; i < HH; i += 256) { float v = proto[aux*HH + i]; ss = fmaf(v, v, ss); }
      ss = wredf(ss);
      if (lane == 0) s_red[wid] = ss;
      __syncthreads();
      if (tid == 0) pnorm[aux] = sqrtf(s_red[0] + s_red[1] + s_red[2] + s_red[3]);
    } else {                              // diversity pair
      const int pi_[10] = {0,0,0,0,1,1,1,2,2,3};
      const int pj_[10] = {1,2,3,4,2,3,4,3,4,4};
      int q = aux - PP, i = pi_[q], j = pj_[q];
      float ss = 0;
      for (int t = tid; t < HH; t += 256) {
        float d = proto[i*HH + t] - proto[j*HH + t];
        ss = fmaf(d, d, ss);
      }
      ss = wredf(ss);
      if (lane == 0) s_red[wid] = ss;
      __syncthreads();
      if (tid == 0) {
        float D = sqrtf(fmaxf(s_red[0] + s_red[1] + s_red[2] + s_red[3], 1e-12f));
        divp[q] = fmaxf(0.5f - D, 0.0f);
      }
    }
  }
}

// ==== node 2: per-row fused GEMV + MDN (160 blocks x 512 threads) — unchanged (R7/R10-verified)
__global__ __launch_bounds__(512) void k2f(
    const float* __restrict__ cs_g, const float* __restrict__ pnorm,
    const float* __restrict__ W1, const float* __restrict__ b1,
    const float* __restrict__ Wpi, const float* __restrict__ bpi,
    const float* __restrict__ Wmu, const float* __restrict__ bmu,
    const float* __restrict__ Wsig, const float* __restrict__ bsig,
    float* __restrict__ mask_g, float* __restrict__ denom_g, double* __restrict__ loss_rows)
{
  __shared__ float s_cs[LL], s_h[LL];
  __shared__ float s_out[16];
  __shared__ float s_par[32]; // logpi[0..4] pi[5..9] mu[10..14] logsig[15..19] invsig[20..24] sig[25..29]
  __shared__ float s_dn[8];
  int tid = threadIdx.x, lane = tid & 63, wid = tid >> 6, n = blockIdx.x;
  float invp = 1.0f / fmaxf(pnorm[n % PP], 1e-12f);
  s_cs[tid] = cs_g[(size_t)n * LL + tid] * invp;   // finish cosine: apply 1/|proto|
  __syncthreads();
  // GEMV: thread = column
  {
    float a0 = 0, a1 = 0, a2 = 0, a3 = 0;
    #pragma unroll 4
    for (int l = 0; l < LL; l += 4) {
      a0 = fmaf(s_cs[l+0], W1[(size_t)(l+0) * LL + tid], a0);
      a1 = fmaf(s_cs[l+1], W1[(size_t)(l+1) * LL + tid], a1);
      a2 = fmaf(s_cs[l+2], W1[(size_t)(l+2) * LL + tid], a2);
      a3 = fmaf(s_cs[l+3], W1[(size_t)(l+3) * LL + tid], a3);
    }
    s_h[tid] = tanhf((a0 + a1) + (a2 + a3) + b1[tid]);
  }
  __syncthreads();
  // 15 projection dots (8 waves, 2 rounds), double accumulation
  for (int o = wid; o < 15; o += 8) {
    int pj = o / 5, k = o % 5;
    const float* W  = (pj == 0) ? Wpi : ((pj == 1) ? Wmu : Wsig);
    const float* bb = (pj == 0) ? bpi : ((pj == 1) ? bmu : bsig);
    double acc = 0;
    for (int l = lane; l < LL; l += 64) acc += (double)s_h[l] * (double)W[l * KK + k];
    acc = wredd(acc);
    if (lane == 0) s_out[o] = (float)(acc + (double)bb[k]);
  }
  __syncthreads();
  if (tid == 0) {
    float x[KK], sh[KK], mx = -INFINITY;
    #pragma unroll
    for (int k = 0; k < KK; k++) { x[k] = s_out[k]; mx = fmaxf(mx, x[k]); }
    float se = 0;
    #pragma unroll
    for (int k = 0; k < KK; k++) { sh[k] = x[k] - mx; se += expf(sh[k]); }
    float lse = logf(se);
    #pragma unroll
    for (int k = 0; k < KK; k++) {
      float lp = sh[k] - lse;
      s_par[k]      = lp;
      s_par[5 + k]  = expf(lp);
      s_par[10 + k] = s_out[5 + k];
      float ls = s_out[10 + k];
      s_par[15 + k] = ls;
      float sg = expf(ls);
      s_par[25 + k] = sg;
      s_par[20 + k] = 1.0f / sg;
    }
  }
  __syncthreads();
  // wave 0: top-5 (JAX tie-break) + NLL in double
  if (wid == 0) {
    float v[8];
    #pragma unroll
    for (int i = 0; i < 8; i++) v[i] = s_cs[lane + i * 64];
    float ys[KK];
    for (int it = 0; it < KK; ++it) {
      float bv = v[0]; int bi = lane;
      #pragma unroll
      for (int i = 1; i < 8; i++) { if (v[i] > bv) { bv = v[i]; bi = lane + i * 64; } }
      #pragma unroll
      for (int off = 32; off; off >>= 1) {
        float ov = __shfl_xor(bv, off, 64);
        int   oi = __shfl_xor(bi, off, 64);
        if (ov > bv || (ov == bv && oi < bi)) { bv = ov; bi = oi; }
      }
      ys[it] = (float)bi;
      if ((bi & 63) == lane) v[bi >> 6] = -INFINITY;
    }
    double ll = 0;
    if (lane < KK) {
      double y = (double)ys[lane];
      double a[KK], m = -1e300;
      #pragma unroll
      for (int j = 0; j < KK; j++) {
        double z = (y - (double)s_par[10 + j]) / (double)s_par[25 + j];
        a[j] = (double)s_par[j] - 0.5 * z * z - (double)s_par[15 + j]
               - 0.91893853320467274178;  // 0.5*log(2*pi)
        if (a[j] > m) m = a[j];
      }
      double se = 0;
      #pragma unroll
      for (int j = 0; j < KK; j++) se += exp(a[j] - m);
      ll = m + log(se);
    }
    ll = wredd(ll);
    if (lane == 0) loss_rows[n] = ll;
  }
  // mask: one token position per thread
  {
    float t = (float)tid, d = 0;
    #pragma unroll
    for (int k = 0; k < KK; k++) {
      float zt = (t - s_par[10 + k]) * s_par[20 + k];
      d += s_par[5 + k] * expf(-0.5f * zt * zt) * s_par[20 + k];
    }
    d *= 0.39894228040143268f;   // 1/sqrt(2*pi)
    mask_g[(size_t)n * LL + tid] = d;
    float r = wredf(d);
    if (lane == 0) s_dn[wid] = r;
  }
  __syncthreads();
  if (tid == 0)
    denom_g[n] = fmaxf(s_dn[0]+s_dn[1]+s_dn[2]+s_dn[3]+s_dn[4]+s_dn[5]+s_dn[6]+s_dn[7], 1e-9f);
}

// ==== node 3: pooling (32 x 6 blocks, 128-h chunks) + fused sim/head — R10-measured-best
__global__ __launch_bounds__(512) void k3h(const float* __restrict__ hidden,
    const float* __restrict__ mask_g, const float* __restrict__ denom_g,
    const float* __restrict__ proto, const float* __restrict__ pnorm,
    const float* __restrict__ fcW, const float* __restrict__ fcb,
    const double* __restrict__ loss_rows, const float* __restrict__ divp,
    float* __restrict__ numzz, int* __restrict__ counter, float* __restrict__ out)
{
  __shared__ float s_m[PP][LL];        // 10 KB
  __shared__ float s_acc[8][PP][128];  // 20 KB
  __shared__ float s_red2[24];
  __shared__ float s_sim[NN];
  __shared__ int s_last;
  int b = blockIdx.x, hc = blockIdx.y;
  int tid = threadIdx.x, wid = tid >> 6, lane = tid & 63;
  for (int i = tid; i < PP * LL; i += 512) s_m[i >> 9][i & (LL - 1)] = mask_g[(size_t)b * PP * LL + i];
  __syncthreads();
  int h0 = hc * 128 + lane * 2;
  const float* hp = hidden + (size_t)b * LL * HH + h0;
  float a0[PP] = {0,0,0,0,0}, a1[PP] = {0,0,0,0,0};
  int lbase = wid * 64;
  #pragma unroll 8
  for (int i = 0; i < 64; i++) {
    int l = lbase + i;
    float2 hv = *(const float2*)(hp + (size_t)l * HH);
    #pragma unroll
    for (int p = 0; p < PP; p++) {
      float m = s_m[p][l];
      a0[p] = fmaf(hv.x, m, a0[p]); a1[p] = fmaf(hv.y, m, a1[p]);
    }
  }
  #pragma unroll
  for (int p = 0; p < PP; p++) { s_acc[wid][p][lane*2] = a0[p]; s_acc[wid][p][lane*2+1] = a1[p]; }
  __syncthreads();
  // epilogue: partial num = sum_h Z*proto, zz = sum_h Z^2 for this 128-h chunk.
  {
    int p1 = tid >> 7, hl1 = tid & 127;       // wave w covers p1 = w>>1 (const per wave)
    float s = 0;
    #pragma unroll
    for (int w = 0; w < 8; w++) s += s_acc[w][p1][hl1];
    float z = s * (1.0f / 512.0f) / denom_g[b * PP + p1];
    float np1 = z * proto[p1 * HH + hc * 128 + hl1];
    float zp1 = z * z;
    np1 = wredf(np1); zp1 = wredf(zp1);
    if (lane == 0) { s_red2[wid * 2] = np1; s_red2[wid * 2 + 1] = zp1; }
  }
  {
    float np2 = 0, zp2 = 0;
    if (tid < 128) {                          // p = 4, waves 0..1
      float s = 0;
      #pragma unroll
      for (int w = 0; w < 8; w++) s += s_acc[w][4][tid];
      float z = s * (1.0f / 512.0f) / denom_g[b * PP + 4];
      np2 = z * proto[4 * HH + hc * 128 + tid];
      zp2 = z * z;
    }
    np2 = wredf(np2); zp2 = wredf(zp2);
    if (lane == 0 && wid < 2) { s_red2[16 + wid * 2] = np2; s_red2[17 + wid * 2] = zp2; }
  }
  __syncthreads();
  if (tid < 10) {
    int p = tid >> 1, r = tid & 1;
    float v = (p < 4) ? (s_red2[4 * p + r] + s_red2[4 * p + 2 + r])
                      : (s_red2[16 + r] + s_red2[18 + r]);
    atomicAdd(&numzz[(b * PP + p) * 2 + r], v);
  }
  // __syncthreads drains vmcnt -> this block's atomics device-visible before counter bump
  __syncthreads();
  if (tid == 0) { __threadfence(); s_last = (atomicAdd(counter, 1) == (BB * 6 - 1)); }
  __syncthreads();
  if (s_last) {
    __threadfence();   // acquire: other blocks' numzz/loss writes
    for (int g = tid; g < NN; g += 512) {
      float num = numzz[2 * g], zz = numzz[2 * g + 1];
      s_sim[g] = num / fmaxf(sqrtf(zz) * pnorm[g % PP], 1e-6f);
    }
    __syncthreads();
    if (tid < BB * CC) {
      int bb2 = tid >> 2, c = tid & 3;
      float s = fcb[c];
      #pragma unroll
      for (int q = 0; q < PP; q++) s = fmaf(s_sim[bb2 * PP + q], fcW[q * CC + c], s);
      out[tid] = s;
    }
    if (wid == 2) {
      double s = 0;
      for (int i = lane; i < NN; i += 64) s += loss_rows[i];
      s = wredd(s);
      if (lane == 0) out[128] = (float)(-s / 800.0);
    }
    if (wid == 3) {
      float s = (lane < 10) ? divp[lane] : 0.0f;
      s = wredf(s);
      if (lane == 0) out[129] = s;
    }
  }
}

extern "C" void kernel_launch(void* const* d_in, const int* in_sizes, int n_in,
                              void* d_out, int out_size, void* d_ws, size_t ws_size,
                              hipStream_t stream)
{
  const float* emb   = (const float*)d_in[0];
  const float* hid   = (const float*)d_in[1];
  const float* proto = (const float*)d_in[2];
  const float* W1    = (const float*)d_in[3];
  const float* b1    = (const float*)d_in[4];
  const float* Wpi   = (const float*)d_in[5];
  const float* bpi   = (const float*)d_in[6];
  const float* Wmu   = (const float*)d_in[7];
  const float* bmu   = (const float*)d_in[8];
  const float* Wsig  = (const float*)d_in[9];
  const float* bsig  = (const float*)d_in[10];
  const float* fcW   = (const float*)d_in[11];
  const float* fcb   = (const float*)d_in[12];
  float* out = (float*)d_out;

  // ws layout (float offsets)
  double* loss_rows = (double*)d_ws;        // floats [0,320)
  float* wsf    = (float*)d_ws;
  float* divp   = wsf + 320;                // 10
  float* pnorm  = wsf + 330;                // 5
  int*   counter= (int*)(wsf + 336);        // 1
  float* numzz  = wsf + 352;                // 320 (num,zz per row)
  float* cs     = wsf + 1024;               // 81920
  float* maskb  = cs + (size_t)NN * LL;     // 81920
  float* denom  = maskb + (size_t)NN * LL;  // 160

  k1f<<<4112, 256, 0, stream>>>(emb, proto, cs, pnorm, divp, counter, numzz);
  k2f<<<NN, 512, 0, stream>>>(cs, pnorm, W1, b1, Wpi, bpi, Wmu, bmu, Wsig, bsig,
                              maskb, denom, loss_rows);
  k3h<<<dim3(BB, 6), 512, 0, stream>>>(hid, maskb, denom, proto, pnorm, fcW, fcb,
                                       loss_rows, divp, numzz, counter, out);
}